// Round 2
// baseline (436.280 us; speedup 1.0000x reference)
//
#include <hip/hip_runtime.h>
#include <hip/hip_bf16.h>

typedef __attribute__((ext_vector_type(8))) short bf16x8;
typedef __attribute__((ext_vector_type(4))) float f32x4;

#define L_SEQ 2048
#define NHEAD 8
#define DHEAD 64
#define DMODEL 512

__device__ __forceinline__ short f2bf(float f) {
    union { float f; unsigned u; } x; x.f = f;
    unsigned r = x.u + 0x7FFFu + ((x.u >> 16) & 1u);
    return (short)(r >> 16);
}

// split f32 -> hi (truncated bf16) + lo (bf16 of exact remainder); hi+lo ~ x to 2^-17 rel
__device__ __forceinline__ void split8(const float* p, bf16x8& hi, bf16x8& lo) {
    #pragma unroll
    for (int i = 0; i < 8; ++i) {
        float x = p[i];
        unsigned uh = __float_as_uint(x) & 0xFFFF0000u;
        hi[i] = (short)(uh >> 16);
        lo[i] = f2bf(x - __uint_as_float(uh));
    }
}

// ---------------------------------------------------------------------------
// Kernel 1: C = y @ W^T with split-bf16 3-term MFMA (near-f32 accuracy).
//   mode 0 (Wq): q = softplus(C); QCS[nh][l][d]    = q*cf*cos(p),
//                                 QCS[nh][l][64+d] = q*cf*sin(p)
//   mode 1 (Wk): k = softplus(C); KCS likewise (cf=1)
//   mode 2 (Wv): VT[nh][d][l] = C (f32, LDS transpose)
// Block: 128 rows x 64 cols (one head), 4 waves. Grid (32, 8, 3).
// ---------------------------------------------------------------------------
__global__ __launch_bounds__(256) void prep_kernel(
    const float* __restrict__ y, const float* __restrict__ positions,
    const float* __restrict__ Wq, const float* __restrict__ Wk, const float* __restrict__ Wv,
    const float* __restrict__ coeff, const float* __restrict__ pw, const float* __restrict__ pb,
    float* __restrict__ QCS, float* __restrict__ KCS, float* __restrict__ VT)
{
    __shared__ float vtile[128][65];
    const int mode = blockIdx.z;
    const float* W = (mode == 0) ? Wq : (mode == 1) ? Wk : Wv;
    const int m_base = blockIdx.x * 128;
    const int h = blockIdx.y;
    const int n_base = h * 64;
    const int tid = threadIdx.x;
    const int lane = tid & 63;
    const int wv = tid >> 6;
    const int lr = lane & 15;
    const int lg = lane >> 4;

    f32x4 acc[2][4];
    #pragma unroll
    for (int t = 0; t < 2; ++t)
        #pragma unroll
        for (int c = 0; c < 4; ++c) acc[t][c] = (f32x4){0.f, 0.f, 0.f, 0.f};

    for (int kk = 0; kk < DMODEL; kk += 32) {
        bf16x8 ah[2], al[2], bh[4], bl[4];
        #pragma unroll
        for (int t = 0; t < 2; ++t) {
            const float* src = y + (size_t)(m_base + wv*32 + t*16 + lr) * DMODEL + kk + lg*8;
            float tmp[8];
            *(float4*)tmp       = *(const float4*)src;
            *(float4*)(tmp + 4) = *(const float4*)(src + 4);
            split8(tmp, ah[t], al[t]);
        }
        #pragma unroll
        for (int c = 0; c < 4; ++c) {
            const float* src = W + (size_t)(n_base + c*16 + lr) * DMODEL + kk + lg*8;
            float tmp[8];
            *(float4*)tmp       = *(const float4*)src;
            *(float4*)(tmp + 4) = *(const float4*)(src + 4);
            split8(tmp, bh[c], bl[c]);
        }
        #pragma unroll
        for (int t = 0; t < 2; ++t)
            #pragma unroll
            for (int c = 0; c < 4; ++c) {
                acc[t][c] = __builtin_amdgcn_mfma_f32_16x16x32_bf16(ah[t], bh[c], acc[t][c], 0, 0, 0);
                acc[t][c] = __builtin_amdgcn_mfma_f32_16x16x32_bf16(ah[t], bl[c], acc[t][c], 0, 0, 0);
                acc[t][c] = __builtin_amdgcn_mfma_f32_16x16x32_bf16(al[t], bh[c], acc[t][c], 0, 0, 0);
            }
    }

    if (mode == 2) {
        #pragma unroll
        for (int t = 0; t < 2; ++t)
            #pragma unroll
            for (int c = 0; c < 4; ++c)
                #pragma unroll
                for (int r = 0; r < 4; ++r)
                    vtile[wv*32 + t*16 + lg*4 + r][c*16 + lr] = acc[t][c][r];
        __syncthreads();
        const int d  = tid >> 2;
        const int l0 = (tid & 3) * 32;
        const int n_idx  = m_base >> 11;
        const int l_glob = (m_base & (L_SEQ - 1)) + l0;
        const int nh = n_idx * NHEAD + h;
        float* dst = VT + ((size_t)nh * DHEAD + d) * L_SEQ + l_glob;
        #pragma unroll
        for (int i = 0; i < 8; ++i) {
            float4 pk;
            pk.x = vtile[l0 + i*4 + 0][d];
            pk.y = vtile[l0 + i*4 + 1][d];
            pk.z = vtile[l0 + i*4 + 2][d];
            pk.w = vtile[l0 + i*4 + 3][d];
            *(float4*)(dst + i*4) = pk;
        }
    } else {
        float* OUT = (mode == 0) ? QCS : KCS;
        #pragma unroll
        for (int t = 0; t < 2; ++t) {
            #pragma unroll
            for (int c = 0; c < 4; ++c) {
                const int d = c*16 + lr;
                const float pwv = pw[n_base + d];
                const float pbv = pb[n_base + d];
                const float cf  = (mode == 0) ? coeff[n_base + d] : 1.0f;
                #pragma unroll
                for (int r = 0; r < 4; ++r) {
                    const int gm = m_base + wv*32 + t*16 + lg*4 + r;
                    const int n_idx = gm >> 11;
                    const int l = gm & (L_SEQ - 1);
                    const float posv = positions[gm];
                    const float x = acc[t][c][r];
                    const float sp = fmaxf(x, 0.f) + log1pf(expf(-fabsf(x)));
                    const float p = pwv * posv + pbv;
                    float sn, cs;
                    sincosf(p, &sn, &cs);
                    const int nh = n_idx * NHEAD + h;
                    const size_t base = ((size_t)nh * L_SEQ + l) * 128;
                    OUT[base + d]      = sp * cf * cs;
                    OUT[base + 64 + d] = sp * cf * sn;
                }
            }
        }
    }
}

// ---------------------------------------------------------------------------
// Kernel 2: causal sum-normalized attention, split-bf16 3-term MFMA.
// Block: 128 q rows, 4 waves (32 rows each). QK^T: K=128 (cos|sin packed).
// S staged in LDS as f32 (XOR swizzle), split at read for PV. V split at load.
// ---------------------------------------------------------------------------
__global__ __launch_bounds__(256) void attn_kernel(
    const float* __restrict__ QCS, const float* __restrict__ KCS,
    const float* __restrict__ VT, float* __restrict__ out)
{
    __shared__ char s_lds[128 * 256];   // 128 rows x 64 f32, swizzled
    const int qt = blockIdx.x;
    const int nh = blockIdx.y;
    const int q_base = qt * 128;
    const int tid = threadIdx.x;
    const int lane = tid & 63;
    const int wv = tid >> 6;
    const int lr = lane & 15;
    const int lg = lane >> 4;

    const float* Q_b = QCS + (size_t)nh * L_SEQ * 128;
    const float* K_b = KCS + (size_t)nh * L_SEQ * 128;
    const float* V_b = VT  + (size_t)nh * DHEAD * L_SEQ;

    // Q fragments (hi/lo), hoisted: [t][kh], kh spans the 128-dim in 32-chunks
    bf16x8 qh[2][4], ql[2][4];
    #pragma unroll
    for (int t = 0; t < 2; ++t)
        #pragma unroll
        for (int kh = 0; kh < 4; ++kh) {
            const int row = q_base + wv*32 + t*16 + lr;
            float tmp[8];
            const float* src = Q_b + (size_t)row * 128 + kh*32 + lg*8;
            *(float4*)tmp       = *(const float4*)src;
            *(float4*)(tmp + 4) = *(const float4*)(src + 4);
            split8(tmp, qh[t][kh], ql[t][kh]);
        }

    f32x4 o_acc[2][4];
    float rsum[2][4];
    #pragma unroll
    for (int t = 0; t < 2; ++t) {
        #pragma unroll
        for (int c = 0; c < 4; ++c) o_acc[t][c] = (f32x4){0.f, 0.f, 0.f, 0.f};
        #pragma unroll
        for (int r = 0; r < 4; ++r) rsum[t][r] = 0.f;
    }

    const int kt_max = 2*qt + 1;
    for (int kt = 0; kt <= kt_max; ++kt) {
        const int k0 = kt * 64;

        f32x4 s[2][4];
        #pragma unroll
        for (int t = 0; t < 2; ++t)
            #pragma unroll
            for (int c = 0; c < 4; ++c) s[t][c] = (f32x4){0.f, 0.f, 0.f, 0.f};

        #pragma unroll
        for (int kh = 0; kh < 4; ++kh) {
            #pragma unroll
            for (int c = 0; c < 4; ++c) {
                const int key = k0 + c*16 + lr;
                float tmp[8];
                const float* src = K_b + (size_t)key * 128 + kh*32 + lg*8;
                *(float4*)tmp       = *(const float4*)src;
                *(float4*)(tmp + 4) = *(const float4*)(src + 4);
                bf16x8 kh_, kl_;
                split8(tmp, kh_, kl_);
                #pragma unroll
                for (int t = 0; t < 2; ++t) {
                    s[t][c] = __builtin_amdgcn_mfma_f32_16x16x32_bf16(qh[t][kh], kh_, s[t][c], 0, 0, 0);
                    s[t][c] = __builtin_amdgcn_mfma_f32_16x16x32_bf16(qh[t][kh], kl_, s[t][c], 0, 0, 0);
                    s[t][c] = __builtin_amdgcn_mfma_f32_16x16x32_bf16(ql[t][kh], kh_, s[t][c], 0, 0, 0);
                }
            }
        }

        const bool domask = (kt >= 2*qt);
        #pragma unroll
        for (int t = 0; t < 2; ++t) {
            #pragma unroll
            for (int c = 0; c < 4; ++c) {
                #pragma unroll
                for (int r = 0; r < 4; ++r) {
                    const int gq = q_base + wv*32 + t*16 + lg*4 + r;
                    const int gk = k0 + c*16 + lr;
                    float v = s[t][c][r];
                    if (domask && gk > gq) v = 0.f;
                    rsum[t][r] += v;
                    const int lrow = wv*32 + t*16 + lg*4 + r;
                    const int byte = lrow*256 + ((((c*16 + lr)*4)) ^ ((lrow & 7) << 5));
                    *(float*)(s_lds + byte) = v;
                }
            }
        }
        __syncthreads();

        #pragma unroll
        for (int kh2 = 0; kh2 < 2; ++kh2) {
            bf16x8 vh[4], vl[4];
            #pragma unroll
            for (int c = 0; c < 4; ++c) {
                float tmp[8];
                const float* src = V_b + (size_t)(c*16 + lr) * L_SEQ + k0 + kh2*32 + lg*8;
                *(float4*)tmp       = *(const float4*)src;
                *(float4*)(tmp + 4) = *(const float4*)(src + 4);
                split8(tmp, vh[c], vl[c]);
            }
            #pragma unroll
            for (int t = 0; t < 2; ++t) {
                const int lrow = wv*32 + t*16 + lr;
                const int base = lrow*256 + ((kh2*128 + lg*32) ^ ((lrow & 7) << 5));
                float tmp[8];
                *(f32x4*)tmp       = *(const f32x4*)(s_lds + base);
                *(f32x4*)(tmp + 4) = *(const f32x4*)(s_lds + base + 16);
                bf16x8 sh, sl;
                split8(tmp, sh, sl);
                #pragma unroll
                for (int c = 0; c < 4; ++c) {
                    o_acc[t][c] = __builtin_amdgcn_mfma_f32_16x16x32_bf16(sh, vh[c], o_acc[t][c], 0, 0, 0);
                    o_acc[t][c] = __builtin_amdgcn_mfma_f32_16x16x32_bf16(sh, vl[c], o_acc[t][c], 0, 0, 0);
                    o_acc[t][c] = __builtin_amdgcn_mfma_f32_16x16x32_bf16(sl, vh[c], o_acc[t][c], 0, 0, 0);
                }
            }
        }
        __syncthreads();
    }

    #pragma unroll
    for (int t = 0; t < 2; ++t)
        #pragma unroll
        for (int r = 0; r < 4; ++r) {
            float v = rsum[t][r];
            v += __shfl_xor(v, 1);
            v += __shfl_xor(v, 2);
            v += __shfl_xor(v, 4);
            v += __shfl_xor(v, 8);
            rsum[t][r] = v;
        }

    const int n_idx = nh >> 3;
    const int h = nh & 7;
    #pragma unroll
    for (int t = 0; t < 2; ++t)
        #pragma unroll
        for (int c = 0; c < 4; ++c)
            #pragma unroll
            for (int r = 0; r < 4; ++r) {
                const int gq = q_base + wv*32 + t*16 + lg*4 + r;
                const int d = c*16 + lr;
                out[((size_t)(n_idx * L_SEQ + gq)) * DMODEL + h*DHEAD + d] =
                    o_acc[t][c][r] / rsum[t][r];
            }
}

extern "C" void kernel_launch(void* const* d_in, const int* in_sizes, int n_in,
                              void* d_out, int out_size, void* d_ws, size_t ws_size,
                              hipStream_t stream) {
    const float* y         = (const float*)d_in[0];
    const float* positions = (const float*)d_in[1];
    const float* Wq        = (const float*)d_in[2];
    const float* Wk        = (const float*)d_in[3];
    const float* Wv        = (const float*)d_in[4];
    const float* coeff     = (const float*)d_in[5];
    const float* pw        = (const float*)d_in[6];
    const float* pb        = (const float*)d_in[7];
    float* out = (float*)d_out;

    // f32 workspace: QCS [16][2048][128], KCS [16][2048][128], VT [16][64][2048]
    const size_t SZQ = (size_t)16 * L_SEQ * 128;   // 4M floats = 16 MB
    float* QCS = (float*)d_ws;
    float* KCS = QCS + SZQ;
    float* VT  = KCS + SZQ;                        // 2M floats = 8 MB

    prep_kernel<<<dim3(32, 8, 3), dim3(256), 0, stream>>>(
        y, positions, Wq, Wk, Wv, coeff, pw, pb, QCS, KCS, VT);
    attn_kernel<<<dim3(16, 16), dim3(256), 0, stream>>>(QCS, KCS, VT, out);
}

// Round 4
// 294.675 us; speedup vs baseline: 1.4805x; 1.4805x over previous
//
#include <hip/hip_runtime.h>
#include <hip/hip_bf16.h>

typedef __attribute__((ext_vector_type(8))) short bf16x8;
typedef __attribute__((ext_vector_type(4))) float f32x4;

#define L_SEQ 2048
#define NHEAD 8
#define DHEAD 64
#define DMODEL 512

__device__ __forceinline__ short f2bf(float f) {
    union { float f; unsigned u; } x; x.f = f;
    unsigned r = x.u + 0x7FFFu + ((x.u >> 16) & 1u);
    return (short)(r >> 16);
}

__device__ __forceinline__ void split1(float x, short& hi, short& lo) {
    unsigned uh = __float_as_uint(x) & 0xFFFF0000u;
    hi = (short)(uh >> 16);
    lo = f2bf(x - __uint_as_float(uh));
}

__device__ __forceinline__ void split8(const float* p, bf16x8& hi, bf16x8& lo) {
    #pragma unroll
    for (int i = 0; i < 8; ++i) {
        float x = p[i];
        unsigned uh = __float_as_uint(x) & 0xFFFF0000u;
        hi[i] = (short)(uh >> 16);
        lo[i] = f2bf(x - __uint_as_float(uh));
    }
}

// ---------------------------------------------------------------------------
// Kernel 1: C = y @ W^T with split-bf16 3-term MFMA (near-f32 accuracy).
//   mode 0 (Wq): q=softplus(C); Qh/Ql[nh][l][0..63]=split(q*cf*cos p),
//                               Qh/Ql[nh][l][64..127]=split(q*cf*sin p)
//   mode 1 (Wk): k=softplus(C); Kh/Kl likewise (cf=1)
//   mode 2 (Wv): Vh/Vl[nh][d][l] = split(C)  (LDS transpose)
// Block: 128 rows x 64 cols (one head), 4 waves. Grid (32, 8, 3).
// ---------------------------------------------------------------------------
__global__ __launch_bounds__(256) void prep_kernel(
    const float* __restrict__ y, const float* __restrict__ positions,
    const float* __restrict__ Wq, const float* __restrict__ Wk, const float* __restrict__ Wv,
    const float* __restrict__ coeff, const float* __restrict__ pw, const float* __restrict__ pb,
    short* __restrict__ Qh, short* __restrict__ Ql,
    short* __restrict__ Kh, short* __restrict__ Kl,
    short* __restrict__ Vh, short* __restrict__ Vl)
{
    __shared__ float vtile[128][65];
    const int mode = blockIdx.z;
    const float* W = (mode == 0) ? Wq : (mode == 1) ? Wk : Wv;
    const int m_base = blockIdx.x * 128;
    const int h = blockIdx.y;
    const int n_base = h * 64;
    const int tid = threadIdx.x;
    const int lane = tid & 63;
    const int wv = tid >> 6;
    const int lr = lane & 15;
    const int lg = lane >> 4;

    f32x4 acc[2][4];
    #pragma unroll
    for (int t = 0; t < 2; ++t)
        #pragma unroll
        for (int c = 0; c < 4; ++c) acc[t][c] = (f32x4){0.f, 0.f, 0.f, 0.f};

    for (int kk = 0; kk < DMODEL; kk += 32) {
        bf16x8 ah[2], al[2], bh[4], bl[4];
        #pragma unroll
        for (int t = 0; t < 2; ++t) {
            const float* src = y + (size_t)(m_base + wv*32 + t*16 + lr) * DMODEL + kk + lg*8;
            float tmp[8];
            *(float4*)tmp       = *(const float4*)src;
            *(float4*)(tmp + 4) = *(const float4*)(src + 4);
            split8(tmp, ah[t], al[t]);
        }
        #pragma unroll
        for (int c = 0; c < 4; ++c) {
            const float* src = W + (size_t)(n_base + c*16 + lr) * DMODEL + kk + lg*8;
            float tmp[8];
            *(float4*)tmp       = *(const float4*)src;
            *(float4*)(tmp + 4) = *(const float4*)(src + 4);
            split8(tmp, bh[c], bl[c]);
        }
        #pragma unroll
        for (int t = 0; t < 2; ++t)
            #pragma unroll
            for (int c = 0; c < 4; ++c) {
                acc[t][c] = __builtin_amdgcn_mfma_f32_16x16x32_bf16(ah[t], bh[c], acc[t][c], 0, 0, 0);
                acc[t][c] = __builtin_amdgcn_mfma_f32_16x16x32_bf16(ah[t], bl[c], acc[t][c], 0, 0, 0);
                acc[t][c] = __builtin_amdgcn_mfma_f32_16x16x32_bf16(al[t], bh[c], acc[t][c], 0, 0, 0);
            }
    }

    if (mode == 2) {
        #pragma unroll
        for (int t = 0; t < 2; ++t)
            #pragma unroll
            for (int c = 0; c < 4; ++c)
                #pragma unroll
                for (int r = 0; r < 4; ++r)
                    vtile[wv*32 + t*16 + lg*4 + r][c*16 + lr] = acc[t][c][r];
        __syncthreads();
        const int d  = tid >> 2;
        const int l0 = (tid & 3) * 32;
        const int n_idx  = m_base >> 11;
        const int l_glob = (m_base & (L_SEQ - 1)) + l0;
        const int nh = n_idx * NHEAD + h;
        const size_t dbase = ((size_t)nh * DHEAD + d) * L_SEQ + l_glob;
        #pragma unroll
        for (int i = 0; i < 4; ++i) {
            bf16x8 ph, pl;
            #pragma unroll
            for (int j = 0; j < 8; ++j) {
                short th, tl;
                split1(vtile[l0 + i*8 + j][d], th, tl);
                ph[j] = th;
                pl[j] = tl;
            }
            *(bf16x8*)(Vh + dbase + i*8) = ph;
            *(bf16x8*)(Vl + dbase + i*8) = pl;
        }
    } else {
        short* OUTh = (mode == 0) ? Qh : Kh;
        short* OUTl = (mode == 0) ? Ql : Kl;
        #pragma unroll
        for (int t = 0; t < 2; ++t) {
            #pragma unroll
            for (int c = 0; c < 4; ++c) {
                const int d = c*16 + lr;
                const float pwv = pw[n_base + d];
                const float pbv = pb[n_base + d];
                const float cf  = (mode == 0) ? coeff[n_base + d] : 1.0f;
                #pragma unroll
                for (int r = 0; r < 4; ++r) {
                    const int gm = m_base + wv*32 + t*16 + lg*4 + r;
                    const int n_idx = gm >> 11;
                    const int l = gm & (L_SEQ - 1);
                    const float posv = positions[gm];
                    const float x = acc[t][c][r];
                    const float sp = fmaxf(x, 0.f) + __logf(1.f + __expf(-fabsf(x)));
                    const float p = pwv * posv + pbv;
                    const float cs = __cosf(p), sn = __sinf(p);
                    const int nh = n_idx * NHEAD + h;
                    const size_t base = ((size_t)nh * L_SEQ + l) * 128;
                    short h1, l1, h2, l2;
                    split1(sp * cf * cs, h1, l1);
                    split1(sp * cf * sn, h2, l2);
                    OUTh[base + d]      = h1;
                    OUTl[base + d]      = l1;
                    OUTh[base + 64 + d] = h2;
                    OUTl[base + 64 + d] = l2;
                }
            }
        }
    }
}

// ---------------------------------------------------------------------------
// Kernel 2: split-K causal attention chunk. Each block = (nh, qt, ci):
// 128 q rows, up to 4 k-steps of 64 keys. Partial O / rowsum accumulated
// into global f32 via atomicAdd (normalization is linear -> order-free).
// Grid (72, 16), 4 waves. 3-term split-bf16 MFMA throughout.
// ---------------------------------------------------------------------------
__global__ __launch_bounds__(256, 3) void attn_kernel(
    const short* __restrict__ Qh, const short* __restrict__ Ql,
    const short* __restrict__ Kh, const short* __restrict__ Kl,
    const short* __restrict__ Vh, const short* __restrict__ Vl,
    float* __restrict__ O_acc, float* __restrict__ rsum_acc)
{
    __shared__ char s_lds[128 * 256];   // 128 rows x 64 f32, XOR-swizzled
    // map blockIdx.x -> (qt, chunk)
    int rem = blockIdx.x, qt = 0;
    for (qt = 0; qt < 16; ++qt) {
        const int nch = (2*qt + 2 + 3) >> 2;
        if (rem < nch) break;
        rem -= nch;
    }
    const int nst = 2*qt + 2;
    const int kt0 = rem * 4;
    const int kt1 = (kt0 + 4 < nst) ? (kt0 + 4) : nst;

    const int nh = blockIdx.y;
    const int q_base = qt * 128;
    const int tid = threadIdx.x;
    const int lane = tid & 63;
    const int wv = tid >> 6;
    const int lr = lane & 15;
    const int lg = lane >> 4;

    const short* Qh_b = Qh + (size_t)nh * L_SEQ * 128;
    const short* Ql_b = Ql + (size_t)nh * L_SEQ * 128;
    const short* Kh_b = Kh + (size_t)nh * L_SEQ * 128;
    const short* Kl_b = Kl + (size_t)nh * L_SEQ * 128;
    const short* Vh_b = Vh + (size_t)nh * DHEAD * L_SEQ;
    const short* Vl_b = Vl + (size_t)nh * DHEAD * L_SEQ;

    bf16x8 qhf[2][4], qlf[2][4];
    #pragma unroll
    for (int t = 0; t < 2; ++t)
        #pragma unroll
        for (int kh = 0; kh < 4; ++kh) {
            const size_t off = (size_t)(q_base + wv*32 + t*16 + lr) * 128 + kh*32 + lg*8;
            qhf[t][kh] = *(const bf16x8*)(Qh_b + off);
            qlf[t][kh] = *(const bf16x8*)(Ql_b + off);
        }

    f32x4 o_acc[2][4];
    float rsum[2][4];
    #pragma unroll
    for (int t = 0; t < 2; ++t) {
        #pragma unroll
        for (int c = 0; c < 4; ++c) o_acc[t][c] = (f32x4){0.f, 0.f, 0.f, 0.f};
        #pragma unroll
        for (int r = 0; r < 4; ++r) rsum[t][r] = 0.f;
    }

    for (int kt = kt0; kt < kt1; ++kt) {
        const int k0 = kt * 64;

        f32x4 s[2][4];
        #pragma unroll
        for (int t = 0; t < 2; ++t)
            #pragma unroll
            for (int c = 0; c < 4; ++c) s[t][c] = (f32x4){0.f, 0.f, 0.f, 0.f};

        #pragma unroll
        for (int kh = 0; kh < 4; ++kh) {
            #pragma unroll
            for (int c = 0; c < 4; ++c) {
                const size_t koff = (size_t)(k0 + c*16 + lr) * 128 + kh*32 + lg*8;
                const bf16x8 kh_ = *(const bf16x8*)(Kh_b + koff);
                const bf16x8 kl_ = *(const bf16x8*)(Kl_b + koff);
                #pragma unroll
                for (int t = 0; t < 2; ++t) {
                    s[t][c] = __builtin_amdgcn_mfma_f32_16x16x32_bf16(qhf[t][kh], kh_, s[t][c], 0, 0, 0);
                    s[t][c] = __builtin_amdgcn_mfma_f32_16x16x32_bf16(qhf[t][kh], kl_, s[t][c], 0, 0, 0);
                    s[t][c] = __builtin_amdgcn_mfma_f32_16x16x32_bf16(qlf[t][kh], kh_, s[t][c], 0, 0, 0);
                }
            }
        }

        const bool domask = (kt >= 2*qt);
        #pragma unroll
        for (int t = 0; t < 2; ++t) {
            #pragma unroll
            for (int c = 0; c < 4; ++c) {
                #pragma unroll
                for (int r = 0; r < 4; ++r) {
                    const int gq = q_base + wv*32 + t*16 + lg*4 + r;
                    const int gk = k0 + c*16 + lr;
                    float v = s[t][c][r];
                    if (domask && gk > gq) v = 0.f;
                    rsum[t][r] += v;
                    const int lrow = wv*32 + t*16 + lg*4 + r;
                    const int byte = lrow*256 + (((c*16 + lr)*4) ^ ((lrow & 7) << 5));
                    *(float*)(s_lds + byte) = v;
                }
            }
        }
        __syncthreads();

        #pragma unroll
        for (int kh2 = 0; kh2 < 2; ++kh2) {
            bf16x8 vh[4], vl[4];
            #pragma unroll
            for (int c = 0; c < 4; ++c) {
                const size_t voff = (size_t)(c*16 + lr) * L_SEQ + k0 + kh2*32 + lg*8;
                vh[c] = *(const bf16x8*)(Vh_b + voff);
                vl[c] = *(const bf16x8*)(Vl_b + voff);
            }
            #pragma unroll
            for (int t = 0; t < 2; ++t) {
                const int lrow = wv*32 + t*16 + lr;
                const int base = lrow*256 + ((kh2*128 + lg*32) ^ ((lrow & 7) << 5));
                float tmp[8];
                *(f32x4*)tmp       = *(const f32x4*)(s_lds + base);
                *(f32x4*)(tmp + 4) = *(const f32x4*)(s_lds + base + 16);
                bf16x8 sh, sl;
                split8(tmp, sh, sl);
                #pragma unroll
                for (int c = 0; c < 4; ++c) {
                    o_acc[t][c] = __builtin_amdgcn_mfma_f32_16x16x32_bf16(sh, vh[c], o_acc[t][c], 0, 0, 0);
                    o_acc[t][c] = __builtin_amdgcn_mfma_f32_16x16x32_bf16(sh, vl[c], o_acc[t][c], 0, 0, 0);
                    o_acc[t][c] = __builtin_amdgcn_mfma_f32_16x16x32_bf16(sl, vh[c], o_acc[t][c], 0, 0, 0);
                }
            }
        }
        __syncthreads();
    }

    // accumulate partial sums
    #pragma unroll
    for (int t = 0; t < 2; ++t)
        #pragma unroll
        for (int r = 0; r < 4; ++r) {
            float v = rsum[t][r];
            v += __shfl_xor(v, 1);
            v += __shfl_xor(v, 2);
            v += __shfl_xor(v, 4);
            v += __shfl_xor(v, 8);
            if (lr == 0) {
                const int gq = q_base + wv*32 + t*16 + lg*4 + r;
                atomicAdd(rsum_acc + nh*L_SEQ + gq, v);
            }
        }

    #pragma unroll
    for (int t = 0; t < 2; ++t)
        #pragma unroll
        for (int c = 0; c < 4; ++c)
            #pragma unroll
            for (int r = 0; r < 4; ++r) {
                const int gq = q_base + wv*32 + t*16 + lg*4 + r;
                atomicAdd(O_acc + ((size_t)nh*L_SEQ + gq)*DHEAD + c*16 + lr, o_acc[t][c][r]);
            }
}

// out[(n*L+l)*512 + h*64+d] = O_acc[(nh*L+l)*64+d] / rsum[nh*L+l]
__global__ __launch_bounds__(256) void div_kernel(
    const float* __restrict__ O_acc, const float* __restrict__ rsum_acc,
    float* __restrict__ out)
{
    const int idx = blockIdx.x * 256 + threadIdx.x;   // 512K threads, 4 floats each
    const int d4 = idx & 15;
    const int l  = (idx >> 4) & (L_SEQ - 1);
    const int nh = idx >> 15;
    const float4 o = *(const float4*)(O_acc + ((size_t)nh*L_SEQ + l)*DHEAD + d4*4);
    const float inv = 1.0f / rsum_acc[nh*L_SEQ + l];
    float4 r;
    r.x = o.x * inv; r.y = o.y * inv; r.z = o.z * inv; r.w = o.w * inv;
    const int n = nh >> 3, h = nh & 7;
    *(float4*)(out + ((size_t)(n*L_SEQ + l))*DMODEL + h*DHEAD + d4*4) = r;
}

extern "C" void kernel_launch(void* const* d_in, const int* in_sizes, int n_in,
                              void* d_out, int out_size, void* d_ws, size_t ws_size,
                              hipStream_t stream) {
    const float* y         = (const float*)d_in[0];
    const float* positions = (const float*)d_in[1];
    const float* Wq        = (const float*)d_in[2];
    const float* Wk        = (const float*)d_in[3];
    const float* Wv        = (const float*)d_in[4];
    const float* coeff     = (const float*)d_in[5];
    const float* pw        = (const float*)d_in[6];
    const float* pb        = (const float*)d_in[7];
    float* out = (float*)d_out;

    const size_t SQK = (size_t)16 * L_SEQ * 128;    // 4M shorts = 8 MB
    const size_t SV  = (size_t)16 * DHEAD * L_SEQ;  // 2M shorts = 4 MB
    short* Qh = (short*)d_ws;
    short* Ql = Qh + SQK;
    short* Kh = Ql + SQK;
    short* Kl = Kh + SQK;
    short* Vh = Kl + SQK;
    short* Vl = Vh + SV;
    float* O_acc    = (float*)(Vl + SV);                       // 16*2048*64 f32 = 8 MB
    float* rsum_acc = O_acc + (size_t)16 * L_SEQ * DHEAD;      // 32K f32 = 128 KB

    (void)hipMemsetAsync(O_acc, 0, ((size_t)16*L_SEQ*DHEAD + 16*L_SEQ) * sizeof(float), stream);
    prep_kernel<<<dim3(32, 8, 3), dim3(256), 0, stream>>>(
        y, positions, Wq, Wk, Wv, coeff, pw, pb, Qh, Ql, Kh, Kl, Vh, Vl);
    attn_kernel<<<dim3(72, 16), dim3(256), 0, stream>>>(
        Qh, Ql, Kh, Kl, Vh, Vl, O_acc, rsum_acc);
    div_kernel<<<dim3(2048), dim3(256), 0, stream>>>(O_acc, rsum_acc, out);
}

// Round 5
// 256.714 us; speedup vs baseline: 1.6995x; 1.1479x over previous
//
#include <hip/hip_runtime.h>
#include <hip/hip_bf16.h>

typedef __attribute__((ext_vector_type(8))) short bf16x8;
typedef __attribute__((ext_vector_type(4))) float f32x4;

#define L_SEQ 2048
#define NHEAD 8
#define DHEAD 64
#define DMODEL 512

__device__ __forceinline__ short f2bf(float f) {
    union { float f; unsigned u; } x; x.f = f;
    unsigned r = x.u + 0x7FFFu + ((x.u >> 16) & 1u);
    return (short)(r >> 16);
}

__device__ __forceinline__ void split1(float x, short& hi, short& lo) {
    unsigned uh = __float_as_uint(x) & 0xFFFF0000u;
    hi = (short)(uh >> 16);
    lo = f2bf(x - __uint_as_float(uh));
}

__device__ __forceinline__ void split8(const float* p, bf16x8& hi, bf16x8& lo) {
    #pragma unroll
    for (int i = 0; i < 8; ++i) {
        float x = p[i];
        unsigned uh = __float_as_uint(x) & 0xFFFF0000u;
        hi[i] = (short)(uh >> 16);
        lo[i] = f2bf(x - __uint_as_float(uh));
    }
}

// ---------------------------------------------------------------------------
// Kernel 1: C = y @ W^T with split-bf16 3-term MFMA (near-f32 accuracy).
//   mode 0 (Wq): q=softplus(C); Qh/Ql[nh][l][0..63]=split(q*cf*cos p),
//                               Qh/Ql[nh][l][64..127]=split(q*cf*sin p)
//   mode 1 (Wk): k=softplus(C); Kh/Kl likewise (cf=1)
//   mode 2 (Wv): Vh/Vl[nh][d][l] = split(C)  (LDS transpose)
// Block: 128 rows x 64 cols (one head), 4 waves. Grid (32, 8, 3).
// ---------------------------------------------------------------------------
__global__ __launch_bounds__(256) void prep_kernel(
    const float* __restrict__ y, const float* __restrict__ positions,
    const float* __restrict__ Wq, const float* __restrict__ Wk, const float* __restrict__ Wv,
    const float* __restrict__ coeff, const float* __restrict__ pw, const float* __restrict__ pb,
    short* __restrict__ Qh, short* __restrict__ Ql,
    short* __restrict__ Kh, short* __restrict__ Kl,
    short* __restrict__ Vh, short* __restrict__ Vl)
{
    __shared__ float vtile[128][65];
    const int mode = blockIdx.z;
    const float* W = (mode == 0) ? Wq : (mode == 1) ? Wk : Wv;
    const int m_base = blockIdx.x * 128;
    const int h = blockIdx.y;
    const int n_base = h * 64;
    const int tid = threadIdx.x;
    const int lane = tid & 63;
    const int wv = tid >> 6;
    const int lr = lane & 15;
    const int lg = lane >> 4;

    f32x4 acc[2][4];
    #pragma unroll
    for (int t = 0; t < 2; ++t)
        #pragma unroll
        for (int c = 0; c < 4; ++c) acc[t][c] = (f32x4){0.f, 0.f, 0.f, 0.f};

    for (int kk = 0; kk < DMODEL; kk += 32) {
        bf16x8 ah[2], al[2], bh[4], bl[4];
        #pragma unroll
        for (int t = 0; t < 2; ++t) {
            const float* src = y + (size_t)(m_base + wv*32 + t*16 + lr) * DMODEL + kk + lg*8;
            float tmp[8];
            *(float4*)tmp       = *(const float4*)src;
            *(float4*)(tmp + 4) = *(const float4*)(src + 4);
            split8(tmp, ah[t], al[t]);
        }
        #pragma unroll
        for (int c = 0; c < 4; ++c) {
            const float* src = W + (size_t)(n_base + c*16 + lr) * DMODEL + kk + lg*8;
            float tmp[8];
            *(float4*)tmp       = *(const float4*)src;
            *(float4*)(tmp + 4) = *(const float4*)(src + 4);
            split8(tmp, bh[c], bl[c]);
        }
        #pragma unroll
        for (int t = 0; t < 2; ++t)
            #pragma unroll
            for (int c = 0; c < 4; ++c) {
                acc[t][c] = __builtin_amdgcn_mfma_f32_16x16x32_bf16(ah[t], bh[c], acc[t][c], 0, 0, 0);
                acc[t][c] = __builtin_amdgcn_mfma_f32_16x16x32_bf16(ah[t], bl[c], acc[t][c], 0, 0, 0);
                acc[t][c] = __builtin_amdgcn_mfma_f32_16x16x32_bf16(al[t], bh[c], acc[t][c], 0, 0, 0);
            }
    }

    if (mode == 2) {
        #pragma unroll
        for (int t = 0; t < 2; ++t)
            #pragma unroll
            for (int c = 0; c < 4; ++c)
                #pragma unroll
                for (int r = 0; r < 4; ++r)
                    vtile[wv*32 + t*16 + lg*4 + r][c*16 + lr] = acc[t][c][r];
        __syncthreads();
        const int d  = tid >> 2;
        const int l0 = (tid & 3) * 32;
        const int n_idx  = m_base >> 11;
        const int l_glob = (m_base & (L_SEQ - 1)) + l0;
        const int nh = n_idx * NHEAD + h;
        const size_t dbase = ((size_t)nh * DHEAD + d) * L_SEQ + l_glob;
        #pragma unroll
        for (int i = 0; i < 4; ++i) {
            bf16x8 ph, pl;
            #pragma unroll
            for (int j = 0; j < 8; ++j) {
                short th, tl;
                split1(vtile[l0 + i*8 + j][d], th, tl);
                ph[j] = th;
                pl[j] = tl;
            }
            *(bf16x8*)(Vh + dbase + i*8) = ph;
            *(bf16x8*)(Vl + dbase + i*8) = pl;
        }
    } else {
        short* OUTh = (mode == 0) ? Qh : Kh;
        short* OUTl = (mode == 0) ? Ql : Kl;
        #pragma unroll
        for (int t = 0; t < 2; ++t) {
            #pragma unroll
            for (int c = 0; c < 4; ++c) {
                const int d = c*16 + lr;
                const float pwv = pw[n_base + d];
                const float pbv = pb[n_base + d];
                const float cf  = (mode == 0) ? coeff[n_base + d] : 1.0f;
                #pragma unroll
                for (int r = 0; r < 4; ++r) {
                    const int gm = m_base + wv*32 + t*16 + lg*4 + r;
                    const int n_idx = gm >> 11;
                    const int l = gm & (L_SEQ - 1);
                    const float posv = positions[gm];
                    const float x = acc[t][c][r];
                    const float sp = fmaxf(x, 0.f) + __logf(1.f + __expf(-fabsf(x)));
                    const float p = pwv * posv + pbv;
                    const float cs = __cosf(p), sn = __sinf(p);
                    const int nh = n_idx * NHEAD + h;
                    const size_t base = ((size_t)nh * L_SEQ + l) * 128;
                    short h1, l1, h2, l2;
                    split1(sp * cf * cs, h1, l1);
                    split1(sp * cf * sn, h2, l2);
                    OUTh[base + d]      = h1;
                    OUTl[base + d]      = l1;
                    OUTh[base + 64 + d] = h2;
                    OUTl[base + 64 + d] = l2;
                }
            }
        }
    }
}

// ---------------------------------------------------------------------------
// Kernel 2: split-K causal attention chunk. Each block = (nh, qt, ci):
// 128 q rows, up to 4 k-steps of 64 keys. Partial O / rowsum accumulated
// into global f32 via atomicAdd (normalization is linear -> order-free).
// Grid (72, 16), 4 waves. 3-term split-bf16 MFMA throughout.
// NOTE: no min-waves in launch_bounds — forcing 3 waves/EU capped VGPR at 84
// vs ~170 live -> scratch spill storm (R4: FETCH 198MB, MfmaUtil 7.6%).
// ---------------------------------------------------------------------------
__global__ __launch_bounds__(256) void attn_kernel(
    const short* __restrict__ Qh, const short* __restrict__ Ql,
    const short* __restrict__ Kh, const short* __restrict__ Kl,
    const short* __restrict__ Vh, const short* __restrict__ Vl,
    float* __restrict__ O_acc, float* __restrict__ rsum_acc)
{
    __shared__ char s_lds[128 * 256];   // 128 rows x 64 f32, XOR-swizzled
    // map blockIdx.x -> (qt, chunk)
    int rem = blockIdx.x, qt = 0;
    for (qt = 0; qt < 16; ++qt) {
        const int nch = (2*qt + 2 + 3) >> 2;
        if (rem < nch) break;
        rem -= nch;
    }
    const int nst = 2*qt + 2;
    const int kt0 = rem * 4;
    const int kt1 = (kt0 + 4 < nst) ? (kt0 + 4) : nst;

    const int nh = blockIdx.y;
    const int q_base = qt * 128;
    const int tid = threadIdx.x;
    const int lane = tid & 63;
    const int wv = tid >> 6;
    const int lr = lane & 15;
    const int lg = lane >> 4;

    const short* Qh_b = Qh + (size_t)nh * L_SEQ * 128;
    const short* Ql_b = Ql + (size_t)nh * L_SEQ * 128;
    const short* Kh_b = Kh + (size_t)nh * L_SEQ * 128;
    const short* Kl_b = Kl + (size_t)nh * L_SEQ * 128;
    const short* Vh_b = Vh + (size_t)nh * DHEAD * L_SEQ;
    const short* Vl_b = Vl + (size_t)nh * DHEAD * L_SEQ;

    bf16x8 qhf[2][4], qlf[2][4];
    #pragma unroll
    for (int t = 0; t < 2; ++t)
        #pragma unroll
        for (int kh = 0; kh < 4; ++kh) {
            const size_t off = (size_t)(q_base + wv*32 + t*16 + lr) * 128 + kh*32 + lg*8;
            qhf[t][kh] = *(const bf16x8*)(Qh_b + off);
            qlf[t][kh] = *(const bf16x8*)(Ql_b + off);
        }

    f32x4 o_acc[2][4];
    float rsum[2][4];
    #pragma unroll
    for (int t = 0; t < 2; ++t) {
        #pragma unroll
        for (int c = 0; c < 4; ++c) o_acc[t][c] = (f32x4){0.f, 0.f, 0.f, 0.f};
        #pragma unroll
        for (int r = 0; r < 4; ++r) rsum[t][r] = 0.f;
    }

    for (int kt = kt0; kt < kt1; ++kt) {
        const int k0 = kt * 64;

        f32x4 s[2][4];
        #pragma unroll
        for (int t = 0; t < 2; ++t)
            #pragma unroll
            for (int c = 0; c < 4; ++c) s[t][c] = (f32x4){0.f, 0.f, 0.f, 0.f};

        #pragma unroll
        for (int kh = 0; kh < 4; ++kh) {
            #pragma unroll
            for (int c = 0; c < 4; ++c) {
                const size_t koff = (size_t)(k0 + c*16 + lr) * 128 + kh*32 + lg*8;
                const bf16x8 kh_ = *(const bf16x8*)(Kh_b + koff);
                const bf16x8 kl_ = *(const bf16x8*)(Kl_b + koff);
                #pragma unroll
                for (int t = 0; t < 2; ++t) {
                    s[t][c] = __builtin_amdgcn_mfma_f32_16x16x32_bf16(qhf[t][kh], kh_, s[t][c], 0, 0, 0);
                    s[t][c] = __builtin_amdgcn_mfma_f32_16x16x32_bf16(qhf[t][kh], kl_, s[t][c], 0, 0, 0);
                    s[t][c] = __builtin_amdgcn_mfma_f32_16x16x32_bf16(qlf[t][kh], kh_, s[t][c], 0, 0, 0);
                }
            }
        }

        const bool domask = (kt >= 2*qt);
        #pragma unroll
        for (int t = 0; t < 2; ++t) {
            #pragma unroll
            for (int c = 0; c < 4; ++c) {
                #pragma unroll
                for (int r = 0; r < 4; ++r) {
                    const int gq = q_base + wv*32 + t*16 + lg*4 + r;
                    const int gk = k0 + c*16 + lr;
                    float v = s[t][c][r];
                    if (domask && gk > gq) v = 0.f;
                    rsum[t][r] += v;
                    const int lrow = wv*32 + t*16 + lg*4 + r;
                    const int byte = lrow*256 + (((c*16 + lr)*4) ^ ((lrow & 7) << 5));
                    *(float*)(s_lds + byte) = v;
                }
            }
        }
        __syncthreads();

        #pragma unroll
        for (int kh2 = 0; kh2 < 2; ++kh2) {
            bf16x8 vh[4], vl[4];
            #pragma unroll
            for (int c = 0; c < 4; ++c) {
                const size_t voff = (size_t)(c*16 + lr) * L_SEQ + k0 + kh2*32 + lg*8;
                vh[c] = *(const bf16x8*)(Vh_b + voff);
                vl[c] = *(const bf16x8*)(Vl_b + voff);
            }
            #pragma unroll
            for (int t = 0; t < 2; ++t) {
                const int lrow = wv*32 + t*16 + lr;
                const int base = lrow*256 + ((kh2*128 + lg*32) ^ ((lrow & 7) << 5));
                float tmp[8];
                *(f32x4*)tmp       = *(const f32x4*)(s_lds + base);
                *(f32x4*)(tmp + 4) = *(const f32x4*)(s_lds + base + 16);
                bf16x8 sh, sl;
                split8(tmp, sh, sl);
                #pragma unroll
                for (int c = 0; c < 4; ++c) {
                    o_acc[t][c] = __builtin_amdgcn_mfma_f32_16x16x32_bf16(sh, vh[c], o_acc[t][c], 0, 0, 0);
                    o_acc[t][c] = __builtin_amdgcn_mfma_f32_16x16x32_bf16(sh, vl[c], o_acc[t][c], 0, 0, 0);
                    o_acc[t][c] = __builtin_amdgcn_mfma_f32_16x16x32_bf16(sl, vh[c], o_acc[t][c], 0, 0, 0);
                }
            }
        }
        __syncthreads();
    }

    // accumulate partial sums
    #pragma unroll
    for (int t = 0; t < 2; ++t)
        #pragma unroll
        for (int r = 0; r < 4; ++r) {
            float v = rsum[t][r];
            v += __shfl_xor(v, 1);
            v += __shfl_xor(v, 2);
            v += __shfl_xor(v, 4);
            v += __shfl_xor(v, 8);
            if (lr == 0) {
                const int gq = q_base + wv*32 + t*16 + lg*4 + r;
                atomicAdd(rsum_acc + nh*L_SEQ + gq, v);
            }
        }

    #pragma unroll
    for (int t = 0; t < 2; ++t)
        #pragma unroll
        for (int c = 0; c < 4; ++c)
            #pragma unroll
            for (int r = 0; r < 4; ++r) {
                const int gq = q_base + wv*32 + t*16 + lg*4 + r;
                atomicAdd(O_acc + ((size_t)nh*L_SEQ + gq)*DHEAD + c*16 + lr, o_acc[t][c][r]);
            }
}

// out[(n*L+l)*512 + h*64+d] = O_acc[(nh*L+l)*64+d] / rsum[nh*L+l]
__global__ __launch_bounds__(256) void div_kernel(
    const float* __restrict__ O_acc, const float* __restrict__ rsum_acc,
    float* __restrict__ out)
{
    const int idx = blockIdx.x * 256 + threadIdx.x;   // 512K threads, 4 floats each
    const int d4 = idx & 15;
    const int l  = (idx >> 4) & (L_SEQ - 1);
    const int nh = idx >> 15;
    const float4 o = *(const float4*)(O_acc + ((size_t)nh*L_SEQ + l)*DHEAD + d4*4);
    const float inv = 1.0f / rsum_acc[nh*L_SEQ + l];
    float4 r;
    r.x = o.x * inv; r.y = o.y * inv; r.z = o.z * inv; r.w = o.w * inv;
    const int n = nh >> 3, h = nh & 7;
    *(float4*)(out + ((size_t)(n*L_SEQ + l))*DMODEL + h*DHEAD + d4*4) = r;
}

extern "C" void kernel_launch(void* const* d_in, const int* in_sizes, int n_in,
                              void* d_out, int out_size, void* d_ws, size_t ws_size,
                              hipStream_t stream) {
    const float* y         = (const float*)d_in[0];
    const float* positions = (const float*)d_in[1];
    const float* Wq        = (const float*)d_in[2];
    const float* Wk        = (const float*)d_in[3];
    const float* Wv        = (const float*)d_in[4];
    const float* coeff     = (const float*)d_in[5];
    const float* pw        = (const float*)d_in[6];
    const float* pb        = (const float*)d_in[7];
    float* out = (float*)d_out;

    const size_t SQK = (size_t)16 * L_SEQ * 128;    // 4M shorts = 8 MB
    const size_t SV  = (size_t)16 * DHEAD * L_SEQ;  // 2M shorts = 4 MB
    short* Qh = (short*)d_ws;
    short* Ql = Qh + SQK;
    short* Kh = Ql + SQK;
    short* Kl = Kh + SQK;
    short* Vh = Kl + SQK;
    short* Vl = Vh + SV;
    float* O_acc    = (float*)(Vl + SV);                       // 16*2048*64 f32 = 8 MB
    float* rsum_acc = O_acc + (size_t)16 * L_SEQ * DHEAD;      // 32K f32 = 128 KB

    (void)hipMemsetAsync(O_acc, 0, ((size_t)16*L_SEQ*DHEAD + 16*L_SEQ) * sizeof(float), stream);
    prep_kernel<<<dim3(32, 8, 3), dim3(256), 0, stream>>>(
        y, positions, Wq, Wk, Wv, coeff, pw, pb, Qh, Ql, Kh, Kl, Vh, Vl);
    attn_kernel<<<dim3(72, 16), dim3(256), 0, stream>>>(
        Qh, Ql, Kh, Kl, Vh, Vl, O_acc, rsum_acc);
    div_kernel<<<dim3(2048), dim3(256), 0, stream>>>(O_acc, rsum_acc, out);
}